// Round 8
// baseline (228.801 us; speedup 1.0000x reference)
//
#include <hip/hip_runtime.h>
#include <hip/hip_cooperative_groups.h>

namespace cg = cooperative_groups;

#define NNODES 2048
#define NHEADS 8
#define NN (NNODES * NNODES)

#define NBLK 1024
#define NTHR (NBLK * 256)   // 262144 threads, all co-resident (4 blocks/CU)

typedef unsigned vuint4  __attribute__((ext_vector_type(4)));
typedef float    vfloat4 __attribute__((ext_vector_type(4)));

// Winner word: [(e+1) : 19 bits][score_q : 13 bits], 0 = no edge.
// Unsigned atomicMax picks the largest e (last-wins, matching numpy
// fancy-assignment), since e+1 occupies the high bits and e is unique.
// Score is carried in the low 13 bits so the dense pass needs NO gathers.

__global__ __launch_bounds__(256, 4) void fused_kernel(
    const int* __restrict__ ei, const float* __restrict__ score,
    const float* __restrict__ W, const float* __restrict__ b,
    int E, unsigned* __restrict__ winner, float* __restrict__ out)
{
    cg::grid_group grid = cg::this_grid();
    const int tid = blockIdx.x * blockDim.x + threadIdx.x;

    // ---- Phase 0: winner = 0 (16 MiB, vuint4 stores, coalesced) ----
#pragma unroll
    for (int i = 0; i < NN / 4 / NTHR; ++i) {
        const vuint4 z = {0u, 0u, 0u, 0u};
        reinterpret_cast<vuint4*>(winner)[tid + i * NTHR] = z;
    }
    grid.sync();

    // ---- Phase 1: per-edge atomicMax of packed (e+1, score_q13) ----
    for (int e = tid; e < E; e += NTHR) {
        const int r = ei[e];
        const int c = ei[E + e];
        const float s = score[e];
        unsigned q = (unsigned)(s * 8192.0f);
        q = q > 8191u ? 8191u : q;
        const unsigned val = (((unsigned)e + 1u) << 13) | q;
        atomicMax(&winner[r * NNODES + c], val);
    }
    grid.sync();

    // ---- Phase 2: dense streaming write. 4 cells/thread/iter,
    // wave covers 256 consecutive cells -> 4 KB contiguous stores/plane. ----
    float Wr[3 * NHEADS], Br[NHEADS];
#pragma unroll
    for (int k = 0; k < 3 * NHEADS; ++k) Wr[k] = W[k];
#pragma unroll
    for (int h = 0; h < NHEADS; ++h) Br[h] = b[h];

#pragma unroll
    for (int g0 = 0; g0 < NN / 4 / NTHR; ++g0) {
        const int g = tid + g0 * NTHR;
        const int cell0 = g << 2;
        const vuint4 w4 = reinterpret_cast<const vuint4*>(winner)[g];
        const unsigned wi[4] = {w4.x, w4.y, w4.z, w4.w};

        const float fr  = (float)(cell0 >> 11);           // row
        const float fc0 = (float)(cell0 & (NNODES - 1));  // first col

        float sv[4];
#pragma unroll
        for (int i = 0; i < 4; ++i)
            sv[i] = ((float)(wi[i] & 8191u) + 0.5f) * (1.0f / 8192.0f);

#pragma unroll
        for (int h = 0; h < NHEADS; ++h) {
            const float W0 = Wr[3 * h + 0], W1 = Wr[3 * h + 1], W2 = Wr[3 * h + 2];
            const float B = Br[h];
            vfloat4 v;
#pragma unroll
            for (int i = 0; i < 4; ++i) {
                const float x = fmaf(fr, W0, fmaf(fc0 + (float)i, W1, fmaf(sv[i], W2, B)));
                const float s = 1.0f / (1.0f + __expf(-x));
                v[i] = (wi[i] != 0u) ? s : 0.0f;
            }
            *reinterpret_cast<vfloat4*>(out + (size_t)h * NN + cell0) = v;
        }
    }
}

extern "C" void kernel_launch(void* const* d_in, const int* in_sizes, int n_in,
                              void* d_out, int out_size, void* d_ws, size_t ws_size,
                              hipStream_t stream) {
    const int*   edge_index = (const int*)d_in[0];   // (2, E) int32
    const float* edge_score = (const float*)d_in[1]; // (E,)
    const float* W          = (const float*)d_in[2]; // (H, 3)
    const float* b          = (const float*)d_in[3]; // (H,)
    float*       out        = (float*)d_out;         // (H, N, N)
    int E = in_sizes[1];

    unsigned* winner = (unsigned*)d_ws;  // 16 MiB scratch

    void* args[] = {(void*)&edge_index, (void*)&edge_score, (void*)&W, (void*)&b,
                    (void*)&E, (void*)&winner, (void*)&out};
    hipLaunchCooperativeKernel((const void*)fused_kernel, dim3(NBLK), dim3(256),
                               args, 0, stream);
}

// Round 9
// 53.230 us; speedup vs baseline: 4.2983x; 4.2983x over previous
//
#include <hip/hip_runtime.h>

#define NNODES 2048
#define NHEADS 8
#define NN (NNODES * NNODES)

typedef int   vint4   __attribute__((ext_vector_type(4)));
typedef float vfloat4 __attribute__((ext_vector_type(4)));

// Fill winner with -1. Grid-strided vuint4 stores, 2048 blocks.
__global__ __launch_bounds__(256) void fill_kernel(vint4* __restrict__ winner) {
    const int t = blockIdx.x * blockDim.x + threadIdx.x;
    const vint4 m1 = {-1, -1, -1, -1};
#pragma unroll
    for (int i = 0; i < NN / 4 / (2048 * 256); ++i)
        winner[t + i * 2048 * 256] = m1;
}

// Resolve duplicate (row,col) scatters as last-edge-index-wins (matches
// numpy fancy-assignment ordering used by the reference).
__global__ __launch_bounds__(256) void edge_kernel(const int* __restrict__ ei, int E,
                                                   int* __restrict__ winner) {
    const int e = blockIdx.x * blockDim.x + threadIdx.x;
    if (e >= E) return;
    const int row = ei[e];
    const int col = ei[E + e];
    atomicMax(&winner[row * NNODES + col], e);
}

// Dense write: 8 cells/thread. Per thread: 2 independent winner int4 reads,
// up to 8 L2-resident score gathers (edge_score is 1 MiB -> replicated in
// each XCD's L2), 64 sigmoids, 16 coalesced float4 stores (wave covers
// 2 KB contiguous per plane).
__global__ __launch_bounds__(256) void write_kernel(const int* __restrict__ winner,
                                                    const float* __restrict__ edge_score,
                                                    const float* __restrict__ W,
                                                    const float* __restrict__ b,
                                                    float* __restrict__ out) {
    const int t = blockIdx.x * blockDim.x + threadIdx.x;
    const int cell0 = t << 3;  // 8 consecutive cells, same row (2048 % 8 == 0)

    const vint4 wa = *reinterpret_cast<const vint4*>(winner + cell0);
    const vint4 wb = *reinterpret_cast<const vint4*>(winner + cell0 + 4);
    const int wi[8] = {wa.x, wa.y, wa.z, wa.w, wb.x, wb.y, wb.z, wb.w};

    const float fr  = (float)(cell0 >> 11);            // row
    const float fc0 = (float)(cell0 & (NNODES - 1));   // first col

    float sc[8];
#pragma unroll
    for (int i = 0; i < 8; ++i) sc[i] = (wi[i] >= 0) ? edge_score[wi[i]] : 0.0f;

#pragma unroll
    for (int h = 0; h < NHEADS; ++h) {
        const float W0 = W[3 * h + 0], W1 = W[3 * h + 1], W2 = W[3 * h + 2];
        const float B = b[h];
        vfloat4 v0, v1;
#pragma unroll
        for (int i = 0; i < 8; ++i) {
            const float x = fmaf(fr, W0, fmaf(fc0 + (float)i, W1, fmaf(sc[i], W2, B)));
            const float s = 1.0f / (1.0f + __expf(-x));
            const float r = (wi[i] >= 0) ? s : 0.0f;
            if (i < 4) v0[i] = r; else v1[i - 4] = r;
        }
        float* base = out + (size_t)h * NN + cell0;
        *reinterpret_cast<vfloat4*>(base)     = v0;
        *reinterpret_cast<vfloat4*>(base + 4) = v1;
    }
}

extern "C" void kernel_launch(void* const* d_in, const int* in_sizes, int n_in,
                              void* d_out, int out_size, void* d_ws, size_t ws_size,
                              hipStream_t stream) {
    const int*   edge_index = (const int*)d_in[0];   // (2, E) int32
    const float* edge_score = (const float*)d_in[1]; // (E,)
    const float* W          = (const float*)d_in[2]; // (H, 3)
    const float* b          = (const float*)d_in[3]; // (H,)
    float*       out        = (float*)d_out;         // (H, N, N)
    const int E = in_sizes[1];

    int* winner = (int*)d_ws;  // 16 MiB scratch

    fill_kernel<<<2048, 256, 0, stream>>>((vint4*)winner);
    edge_kernel<<<(E + 255) / 256, 256, 0, stream>>>(edge_index, E, winner);
    write_kernel<<<NN / (8 * 256), 256, 0, stream>>>(winner, edge_score, W, b, out);
}